// Round 1
// 486.999 us; speedup vs baseline: 1.3596x; 1.3596x over previous
//
#include <hip/hip_runtime.h>
#include <stdint.h>

#define NB   256
#define NN   343
#define CC   256
#define NH   8
#define HD   32
#define NWIN 64
#define MM   (NB*NN)          // 87808
#define SCALE_ 0.17677669529663689f
#define LOG2E_ 1.4426950408889634f

typedef unsigned int u32;
typedef unsigned short u16;
typedef float f4 __attribute__((ext_vector_type(4)));
typedef short s8v __attribute__((ext_vector_type(8)));
typedef short s4v __attribute__((ext_vector_type(4)));
typedef _Float16 h8 __attribute__((ext_vector_type(8)));
typedef _Float16 h4 __attribute__((ext_vector_type(4)));

// ws layout (bytes); total 229,077,536
#define OFF_Q    0ull
#define OFF_K    44957696ull           // 87808*256*2
#define OFF_V    89915392ull
#define OFF_XH   134873088ull          // x as fp16, 45 MB (reused for bm tables after k_qkv)
#define OFF_CTXH 179830784ull          // ctx as fp16, 45 MB
#define OFF_BIAS 224788480ull          // (unused now)
#define OFF_WT   228553248ull          // qkv_w^T fp16 [768][256]
#define OFF_PWT  228946464ull          // proj_w^T fp16 [256][256]

// bm tables live in the xh region (dead after k_qkv):
// m16[w][i][lc][24] f16 : 64*343*16*24*2 = 16,859,136 B
// b16[h][i][lc][24] f16 :  8*343*16*24*2 =  2,107,392 B   (total 18.97 MB <= 44.96 MB)
#define OFF_M16  OFF_XH
#define OFF_B16  (OFF_XH + 16859136ull)
#define BMROW 24

__device__ __forceinline__ u16 f2bf(float f){
  u32 u = __float_as_uint(f);
  u = u + 0x7fffu + ((u >> 16) & 1u);   // RNE
  return (u16)(u >> 16);
}
__device__ __forceinline__ u16 f2h(float f){
  _Float16 h = (_Float16)f;
  return __builtin_bit_cast(u16, h);
}
__device__ __forceinline__ void cp16(const void* g, void* s){
  __builtin_amdgcn_global_load_lds(
    (const __attribute__((address_space(1))) unsigned int*)g,
    (__attribute__((address_space(3))) unsigned int*)s, 16, 0, 0);
}

// ---------------- K0b: x fp32 -> fp16 ----------------
// 22478848 elems, 8/thread, grid 10976 exact
__global__ __launch_bounds__(256) void k_cvt_x(const float* __restrict__ x,
                                               _Float16* __restrict__ xh){
  size_t i0 = ((size_t)blockIdx.x*256 + threadIdx.x)*8;
  float4 a = *(const float4*)(x + i0);
  float4 b = *(const float4*)(x + i0 + 4);
  ushort4 pk[2];
  pk[0].x=f2h(a.x); pk[0].y=f2h(a.y); pk[0].z=f2h(a.z); pk[0].w=f2h(a.w);
  pk[1].x=f2h(b.x); pk[1].y=f2h(b.y); pk[1].z=f2h(b.z); pk[1].w=f2h(b.w);
  *(uint4*)(xh + i0) = *(uint4*)&pk[0];
}

// ---------------- K0c: transpose+convert weights ----------------
__global__ __launch_bounds__(256) void k_cvt_w(const float* __restrict__ qw,
                                               const float* __restrict__ pw,
                                               _Float16* __restrict__ wT,
                                               _Float16* __restrict__ pwT){
  int idx = blockIdx.x*256 + threadIdx.x;
  int row = idx >> 5;
  int k0  = (idx & 31) << 3;
  const float* src; int stride; _Float16* dst;
  if (row < 768){ src = qw + row;        stride = 768; dst = wT  + (size_t)row*256 + k0; }
  else          { src = pw + (row-768);  stride = 256; dst = pwT + (size_t)(row-768)*256 + k0; }
  ushort4 pk[2];
  u16* p = (u16*)&pk[0];
  #pragma unroll
  for (int j=0;j<8;j++) p[j] = f2h(src[(size_t)(k0+j)*stride]);
  *(uint4*)dst = *(uint4*)&pk[0];
}

// ---------------- K0d: fused-layout f16 bias/mask tables ----------------
// thread = one (tbl_id, i, lc) row of 24 f16. tbl_id<64: mask w; >=64: bias h.
// layout: [tbl][i][lc][jt] with logical col = jt*16+lc; col>=NN or jt>=22 -> -inf
__global__ __launch_bounds__(256) void k_bm16(const float* __restrict__ mask,
                                              const float* __restrict__ tbl,
                                              const int* __restrict__ ridx,
                                              _Float16* __restrict__ m16,
                                              _Float16* __restrict__ b16){
  int idx = blockIdx.x*256 + threadIdx.x;
  const int tot = 72*NN*16;
  if (idx >= tot) return;
  int tb   = idx / (NN*16);
  int rest = idx - tb*(NN*16);
  int i  = rest >> 4;
  int lc = rest & 15;
  const u16 NEGINF = 0xFC00u;
  u16 buf[BMROW];
  if (tb < 64){
    const float* mrow = mask + ((size_t)tb*NN + i)*NN;
    #pragma unroll
    for (int jt=0;jt<BMROW;jt++){
      int col = jt*16 + lc;
      buf[jt] = (jt < 22 && col < NN) ? f2h(mrow[col]) : NEGINF;
    }
    uint4* dst = (uint4*)(m16 + (((size_t)tb*NN + i)*16 + lc)*BMROW);
    uint4* s = (uint4*)buf;
    dst[0]=s[0]; dst[1]=s[1]; dst[2]=s[2];
  } else {
    int h = tb - 64;
    const int* rrow = ridx + (size_t)i*NN;
    #pragma unroll
    for (int jt=0;jt<BMROW;jt++){
      int col = jt*16 + lc;
      buf[jt] = (jt < 22 && col < NN) ? f2h(tbl[rrow[col]*NH + h]) : NEGINF;
    }
    uint4* dst = (uint4*)(b16 + (((size_t)h*NN + i)*16 + lc)*BMROW);
    uint4* s = (uint4*)buf;
    dst[0]=s[0]; dst[1]=s[1]; dst[2]=s[2];
  }
}

// ---------------- K1: qkv GEMM via fp16 MFMA ----------------
__global__ __launch_bounds__(256,4) void k_qkv(const _Float16* __restrict__ xh,
                                               const _Float16* __restrict__ wT,
                                               const float* __restrict__ qkvb,
                                               u16* __restrict__ qws,
                                               u16* __restrict__ kws,
                                               u16* __restrict__ vws){
  const int nt = blockIdx.x % 6;
  const int mt = blockIdx.x / 6;
  const int m0 = mt*128, n0 = nt*128;
  __shared__ _Float16 As[128*32];
  __shared__ _Float16 Bs[128*32];
  const int t = threadIdx.x;
  const int wv = t >> 6, ln = t & 63, lc = ln & 15, lq = ln >> 4;
  const int wm = wv & 1, wn = wv >> 1;
  const _Float16* ga = xh + (size_t)(m0 + (t>>2))*CC + (t&3)*8;
  const _Float16* gb = wT + (size_t)(n0 + (t>>2))*CC + (t&3)*8;
  f4 acc[4][4];
  #pragma unroll
  for (int i=0;i<4;i++)
    #pragma unroll
    for (int j=0;j<4;j++) acc[i][j] = (f4){0.f,0.f,0.f,0.f};
  for (int kc=0; kc<256; kc+=32){
    __syncthreads();
    cp16(ga + kc,          As + t*8);
    cp16(ga + kc + 64*CC,  As + 2048 + t*8);
    cp16(gb + kc,          Bs + t*8);
    cp16(gb + kc + 64*CC,  Bs + 2048 + t*8);
    __syncthreads();
    h8 af[4], bf[4];
    #pragma unroll
    for (int mi=0;mi<4;mi++) af[mi] = *(const h8*)(As + (wm*64 + mi*16 + lc)*32 + lq*8);
    #pragma unroll
    for (int ni=0;ni<4;ni++) bf[ni] = *(const h8*)(Bs + (wn*64 + ni*16 + lc)*32 + lq*8);
    #pragma unroll
    for (int mi=0;mi<4;mi++)
      #pragma unroll
      for (int ni=0;ni<4;ni++)
        acc[mi][ni] = __builtin_amdgcn_mfma_f32_16x16x32_f16(af[mi], bf[ni], acc[mi][ni], 0,0,0);
  }
  float bias4[4];
  int   nidx[4];
  #pragma unroll
  for (int ni=0;ni<4;ni++){
    int n = n0 + wn*64 + ni*16 + lc;
    nidx[ni] = n;
    bias4[ni] = qkvb[n];
  }
  #pragma unroll
  for (int mi=0;mi<4;mi++){
    #pragma unroll
    for (int r=0;r<4;r++){
      int m = m0 + wm*64 + mi*16 + lq*4 + r;
      int b = m / NN;
      int i = m - b*NN;
      #pragma unroll
      for (int ni=0;ni<4;ni++){
        int n = nidx[ni];
        int s = n >> 8, h = (n >> 5) & 7, d = n & 31;
        size_t off = ((size_t)(b*NH + h)*NN + i)*HD + d;
        float val = acc[mi][ni][r] + bias4[ni];
        if      (s == 0) qws[off] = f2bf(val*SCALE_);
        else if (s == 1) kws[off] = f2bf(val);
        else             vws[off] = f2h(val);
      }
    }
  }
}

// ---------------- K2: MFMA flash attention ----------------
// grid = 2048 (b,h), block 256 (4 waves)
#define KSTR 36
#define VSTR 364
#define PSTR 36
__global__ __launch_bounds__(256,3) void k_attn(const u16* __restrict__ qws,
                                                const u16* __restrict__ kws,
                                                const u16* __restrict__ vws,
                                                const _Float16* __restrict__ m16,
                                                const _Float16* __restrict__ b16,
                                                u16* __restrict__ ctxh){
  __shared__ u16 Klds[352*KSTR];
  __shared__ u16 Vt[HD*VSTR];
  __shared__ _Float16 Pch[4][16*PSTR];
  const int bh = blockIdx.x;
  const int b = bh >> 3, h = bh & 7, w = b & (NWIN-1);
  const size_t kvbase = (size_t)bh * (NN*HD);
  const int t = threadIdx.x;
  for (int task = t; task < 352*4; task += 256){
    int j = task >> 2, d0 = (task & 3) << 3;
    uint4 val = {0u,0u,0u,0u};
    if (j < NN) val = *(const uint4*)(kws + kvbase + j*HD + d0);
    *(uint2*)&Klds[j*KSTR + d0]     = make_uint2(val.x, val.y);
    *(uint2*)&Klds[j*KSTR + d0 + 4] = make_uint2(val.z, val.w);
  }
  for (int task = t; task < 88*4; task += 256){
    int jg = task >> 2, d0 = (task & 3) << 3;
    int j0 = jg*4;
    uint4 r0={0,0,0,0}, r1={0,0,0,0}, r2={0,0,0,0}, r3={0,0,0,0};
    const u16* vsrc = vws + kvbase;
    if (j0   < NN) r0 = *(const uint4*)(vsrc + (size_t)(j0  )*HD + d0);
    if (j0+1 < NN) r1 = *(const uint4*)(vsrc + (size_t)(j0+1)*HD + d0);
    if (j0+2 < NN) r2 = *(const uint4*)(vsrc + (size_t)(j0+2)*HD + d0);
    if (j0+3 < NN) r3 = *(const uint4*)(vsrc + (size_t)(j0+3)*HD + d0);
    const u32* p0=(const u32*)&r0; const u32* p1=(const u32*)&r1;
    const u32* p2=(const u32*)&r2; const u32* p3=(const u32*)&r3;
    #pragma unroll
    for (int e=0;e<8;e++){
      int sh = (e&1)*16;
      ushort4 c4;
      c4.x = (u16)(p0[e>>1] >> sh);
      c4.y = (u16)(p1[e>>1] >> sh);
      c4.z = (u16)(p2[e>>1] >> sh);
      c4.w = (u16)(p3[e>>1] >> sh);
      *(ushort4*)&Vt[(d0+e)*VSTR + j0] = c4;
    }
  }
  __syncthreads();
  const int wv = t >> 6, ln = t & 63;
  const int lc = ln & 15, lq = ln >> 4;
  _Float16* pch = &Pch[wv][0];
  const _Float16* mtab = m16 + (size_t)w*((size_t)NN*16*BMROW);
  const _Float16* btab = b16 + (size_t)h*((size_t)NN*16*BMROW);
  const f4 z4 = {0.f,0.f,0.f,0.f};
  for (int sub = wv; sub < 22; sub += 4){
    int qrow = sub*16 + lc; if (qrow > NN-1) qrow = NN-1;
    s8v qa = *(const s8v*)(qws + kvbase + (size_t)qrow*HD + lq*8);
    f4 acc[22];
    #pragma unroll
    for (int jt=0; jt<22; jt++){
      const u16* kp = &Klds[(jt*16+lc)*KSTR + lq*8];
      s4v k0 = *(const s4v*)kp;
      s4v k1 = *(const s4v*)(kp+4);
      s8v bk = {k0[0],k0[1],k0[2],k0[3],k1[0],k1[1],k1[2],k1[3]};
      acc[jt] = __builtin_amdgcn_mfma_f32_16x16x32_bf16(qa, bk, z4, 0,0,0);
    }
    float l[4];
    #pragma unroll
    for (int r=0;r<4;r++){
      int i = sub*16 + lq*4 + r; if (i > NN-1) i = NN-1;
      const _Float16* mp = mtab + ((size_t)i*16 + lc)*BMROW;
      const _Float16* bp = btab + ((size_t)i*16 + lc)*BMROW;
      h8 m0 = *(const h8*)mp;
      h8 m1 = *(const h8*)(mp+8);
      h8 m2 = *(const h8*)(mp+16);
      h8 b0 = *(const h8*)bp;
      h8 b1 = *(const h8*)(bp+8);
      h8 b2 = *(const h8*)(bp+16);
      h8 s0 = m0 + b0;
      h8 s1 = m1 + b1;
      h8 s2 = m2 + b2;
      float mx0=-INFINITY, mx1=-INFINITY, mx2=-INFINITY, mx3=-INFINITY;
      #pragma unroll
      for (int jt=0; jt<22; jt++){
        float bmv = (float)(jt<8 ? s0[jt] : (jt<16 ? s1[jt-8] : s2[jt-16]));
        float sv = acc[jt][r] + bmv;
        acc[jt][r] = sv;
        if      ((jt&3)==0) mx0 = fmaxf(mx0, sv);
        else if ((jt&3)==1) mx1 = fmaxf(mx1, sv);
        else if ((jt&3)==2) mx2 = fmaxf(mx2, sv);
        else                mx3 = fmaxf(mx3, sv);
      }
      float mx = fmaxf(fmaxf(mx0,mx1), fmaxf(mx2,mx3));
      mx = fmaxf(mx, __shfl_xor(mx, 1));
      mx = fmaxf(mx, __shfl_xor(mx, 2));
      mx = fmaxf(mx, __shfl_xor(mx, 4));
      mx = fmaxf(mx, __shfl_xor(mx, 8));
      float mxl = mx * LOG2E_;
      float p0=0.f, p1=0.f, p2=0.f, p3=0.f;
      #pragma unroll
      for (int jt=0; jt<22; jt++){
        float p = exp2f(__builtin_fmaf(acc[jt][r], LOG2E_, -mxl));
        acc[jt][r] = p;
        if      ((jt&3)==0) p0 += p;
        else if ((jt&3)==1) p1 += p;
        else if ((jt&3)==2) p2 += p;
        else                p3 += p;
      }
      float s_ = (p0+p1)+(p2+p3);
      s_ += __shfl_xor(s_, 1);
      s_ += __shfl_xor(s_, 2);
      s_ += __shfl_xor(s_, 4);
      s_ += __shfl_xor(s_, 8);
      l[r] = s_;
    }
    f4 o0 = z4, o1 = z4;
    #pragma unroll
    for (int kt=0; kt<11; kt++){
      #pragma unroll
      for (int jp=0; jp<2; jp++){
        int jt = kt*2 + jp;
        #pragma unroll
        for (int r=0;r<4;r++)
          pch[(lq*4+r)*PSTR + jp*16 + lc] = (_Float16)acc[jt][r];
      }
      const _Float16* pap = pch + lc*PSTR + lq*8;
      h4 a0 = *(const h4*)pap;
      h4 a1 = *(const h4*)(pap+4);
      h8 pa = {a0[0],a0[1],a0[2],a0[3],a1[0],a1[1],a1[2],a1[3]};
      const _Float16* vp0 = (const _Float16*)&Vt[(lc   )*VSTR + kt*32 + lq*8];
      const _Float16* vp1 = (const _Float16*)&Vt[(lc+16)*VSTR + kt*32 + lq*8];
      h4 b00 = *(const h4*)vp0; h4 b01 = *(const h4*)(vp0+4);
      h4 b10 = *(const h4*)vp1; h4 b11 = *(const h4*)(vp1+4);
      h8 vb0 = {b00[0],b00[1],b00[2],b00[3],b01[0],b01[1],b01[2],b01[3]};
      h8 vb1 = {b10[0],b10[1],b10[2],b10[3],b11[0],b11[1],b11[2],b11[3]};
      o0 = __builtin_amdgcn_mfma_f32_16x16x32_f16(pa, vb0, o0, 0,0,0);
      o1 = __builtin_amdgcn_mfma_f32_16x16x32_f16(pa, vb1, o1, 0,0,0);
    }
    #pragma unroll
    for (int r=0;r<4;r++){
      int i = sub*16 + lq*4 + r;
      if (i < NN){
        float inv = __builtin_amdgcn_rcpf(l[r]);
        u16* op = ctxh + ((size_t)b*NN + i)*CC + h*HD;
        op[lc]    = f2h(o0[r]*inv);
        op[lc+16] = f2h(o1[r]*inv);
      }
    }
  }
}

// ---------------- K3: proj GEMM via fp16 MFMA ----------------
__global__ __launch_bounds__(256,4) void k_proj(const _Float16* __restrict__ ctxh,
                                                const _Float16* __restrict__ pwT,
                                                const float* __restrict__ pb,
                                                float* __restrict__ out){
  const int nt = blockIdx.x & 1;
  const int mt = blockIdx.x >> 1;
  const int m0 = mt*128, n0 = nt*128;
  __shared__ _Float16 As[128*32];
  __shared__ _Float16 Bs[128*32];
  const int t = threadIdx.x;
  const int wv = t >> 6, ln = t & 63, lc = ln & 15, lq = ln >> 4;
  const int wm = wv & 1, wn = wv >> 1;
  const _Float16* ga = ctxh + (size_t)(m0 + (t>>2))*CC + (t&3)*8;
  const _Float16* gb = pwT  + (size_t)(n0 + (t>>2))*CC + (t&3)*8;
  f4 acc[4][4];
  #pragma unroll
  for (int i=0;i<4;i++)
    #pragma unroll
    for (int j=0;j<4;j++) acc[i][j] = (f4){0.f,0.f,0.f,0.f};
  for (int kc=0; kc<256; kc+=32){
    __syncthreads();
    cp16(ga + kc,          As + t*8);
    cp16(ga + kc + 64*CC,  As + 2048 + t*8);
    cp16(gb + kc,          Bs + t*8);
    cp16(gb + kc + 64*CC,  Bs + 2048 + t*8);
    __syncthreads();
    h8 af[4], bf[4];
    #pragma unroll
    for (int mi=0;mi<4;mi++) af[mi] = *(const h8*)(As + (wm*64 + mi*16 + lc)*32 + lq*8);
    #pragma unroll
    for (int ni=0;ni<4;ni++) bf[ni] = *(const h8*)(Bs + (wn*64 + ni*16 + lc)*32 + lq*8);
    #pragma unroll
    for (int mi=0;mi<4;mi++)
      #pragma unroll
      for (int ni=0;ni<4;ni++)
        acc[mi][ni] = __builtin_amdgcn_mfma_f32_16x16x32_f16(af[mi], bf[ni], acc[mi][ni], 0,0,0);
  }
  float bias4[4];
  #pragma unroll
  for (int ni=0;ni<4;ni++) bias4[ni] = pb[n0 + wn*64 + ni*16 + lc];
  #pragma unroll
  for (int mi=0;mi<4;mi++){
    #pragma unroll
    for (int r=0;r<4;r++){
      int m = m0 + wm*64 + mi*16 + lq*4 + r;
      float* orow = out + (size_t)m*CC + n0 + wn*64;
      #pragma unroll
      for (int ni=0;ni<4;ni++)
        orow[ni*16 + lc] = acc[mi][ni][r] + bias4[ni];
    }
  }
}

extern "C" void kernel_launch(void* const* d_in, const int* in_sizes, int n_in,
                              void* d_out, int out_size, void* d_ws, size_t ws_size,
                              hipStream_t stream){
  (void)in_sizes; (void)n_in; (void)out_size; (void)ws_size;
  const float* x   = (const float*)d_in[0];
  const float* msk = (const float*)d_in[1];
  const float* qw  = (const float*)d_in[2];
  const float* qb  = (const float*)d_in[3];
  const float* pw  = (const float*)d_in[4];
  const float* pb  = (const float*)d_in[5];
  const float* tbl = (const float*)d_in[6];
  const int*   rix = (const int*)d_in[7];
  float* out = (float*)d_out;
  char* ws = (char*)d_ws;
  u16*      qws    = (u16*)(ws + OFF_Q);
  u16*      kws    = (u16*)(ws + OFF_K);
  u16*      vws    = (u16*)(ws + OFF_V);
  _Float16* xh     = (_Float16*)(ws + OFF_XH);
  _Float16* ctxh   = (_Float16*)(ws + OFF_CTXH);
  _Float16* wT     = (_Float16*)(ws + OFF_WT);
  _Float16* pwT    = (_Float16*)(ws + OFF_PWT);
  _Float16* m16    = (_Float16*)(ws + OFF_M16);
  _Float16* b16    = (_Float16*)(ws + OFF_B16);

  hipLaunchKernelGGL(k_cvt_x, dim3(10976), dim3(256), 0, stream, x, xh);
  hipLaunchKernelGGL(k_cvt_w, dim3(128), dim3(256), 0, stream, qw, pw, wT, pwT);
  hipLaunchKernelGGL(k_qkv,   dim3(686*6), dim3(256), 0, stream, xh, wT, qb, qws, kws, vws);
  // m16/b16 overwrite the xh region -> must run after k_qkv (stream-ordered)
  hipLaunchKernelGGL(k_bm16,  dim3((72*NN*16 + 255)/256), dim3(256), 0, stream, msk, tbl, rix, m16, b16);
  hipLaunchKernelGGL(k_attn,  dim3(NB*NH), dim3(256), 0, stream, qws, kws, vws, m16, b16, (u16*)ctxh);
  hipLaunchKernelGGL(k_proj,  dim3(686*2), dim3(256), 0, stream, ctxh, pwT, pb, out);
}